// Round 7
// baseline (997.616 us; speedup 1.0000x reference)
//
#include <hip/hip_runtime.h>

#define EDGES 1000000
#define NODES 100000
#define ET 128   // edges per tile
#define NB 64    // nodes per block (node_kernel)
#define NBLK ((NODES + NB - 1) / NB)  // 1563

typedef short short8 __attribute__((ext_vector_type(8)));
typedef float floatx4 __attribute__((ext_vector_type(4)));
typedef unsigned int u32x2 __attribute__((ext_vector_type(2)));

#define MFMA(a, b, c) __builtin_amdgcn_mfma_f32_16x16x32_bf16(a, b, c, 0, 0, 0)

// ws layout (bytes)
#define WS_WX1 0        // 32768: Wx1 bf16 frags
#define WS_WX2 32768    // 16384: Wx2 frags
#define WS_WP1 49152    // 16384: Wp1 frags
#define WS_MISC 65536   // 2048: biases etc (floats)
#define WS_OFF 68608    // off[100128] int = 400512 B (CSR offsets, padded)
#define WS_CNT 469504   // counts/cursor[100000] int = 400000 B (aliased)
#define WS_SREC 917504  // uint2[EDGES] = 8 MB sorted (row,col) records
// scan temporaries alias the srec region (they die before scatter writes srec):
#define WS_TMP WS_SREC                 // int[100352] inclusive per-block scans
#define WS_BSUM (WS_SREC + 401408)     // int[98] block sums
#define WS_BSUMX (WS_SREC + 402432)    // int[128] exclusive-scanned block sums

__device__ __forceinline__ unsigned short f2bf(float f) {
  union { float f; unsigned int u; } c;
  c.f = f;
  unsigned int u = c.u;
  u += 0x7fffu + ((u >> 16) & 1u);
  return (unsigned short)(u >> 16);
}

__device__ __forceinline__ unsigned int pack2bf(float lo, float hi) {
  return (unsigned int)f2bf(lo) | ((unsigned int)f2bf(hi) << 16);
}

__device__ __forceinline__ float fast_silu(float v) {
#if __has_builtin(__builtin_amdgcn_exp2f) && __has_builtin(__builtin_amdgcn_rcpf)
  float e = __builtin_amdgcn_exp2f(-1.44269504088896340736f * v);
  return v * __builtin_amdgcn_rcpf(1.0f + e);
#else
  return v / (1.0f + __expf(-v));
#endif
}

__global__ __launch_bounds__(256) void prep_kernel(
    const float* __restrict__ Wx1, const float* __restrict__ Wx2,
    const float* __restrict__ Wp1, const float* __restrict__ bx1,
    const float* __restrict__ bx2, const float* __restrict__ bp1,
    const float* __restrict__ Wp2, const float* __restrict__ bp2,
    unsigned char* __restrict__ ws) {
  const int t = blockIdx.x * 256 + threadIdx.x;
  const int nthr = gridDim.x * 256;

  for (int task = t; task < 2048; task += nthr) {  // Wx1[0:128][0:128]
    const int n = task & 127;
    const int kb = task >> 7;
    const int k0 = kb << 3;
    unsigned int d[4];
#pragma unroll
    for (int i = 0; i < 4; ++i)
      d[i] = pack2bf(Wx1[(k0 + 2 * i) * 128 + n], Wx1[(k0 + 2 * i + 1) * 128 + n]);
    const int lane = ((kb & 3) << 4) | (n & 15);
    const int frag = ((kb >> 2) << 3) | (n >> 4);
    *(uint4*)(ws + WS_WX1 + ((size_t)(frag * 64 + lane) << 4)) =
        make_uint4(d[0], d[1], d[2], d[3]);
  }
  for (int task = t; task < 1024; task += nthr) {  // Wx2[0:128][0:64]
    const int n = task & 63;
    const int kb = task >> 6;
    const int k0 = kb << 3;
    unsigned int d[4];
#pragma unroll
    for (int i = 0; i < 4; ++i)
      d[i] = pack2bf(Wx2[(k0 + 2 * i) * 64 + n], Wx2[(k0 + 2 * i + 1) * 64 + n]);
    const int lane = ((kb & 3) << 4) | (n & 15);
    const int frag = ((kb >> 2) << 2) | (n >> 4);
    *(uint4*)(ws + WS_WX2 + ((size_t)(frag * 64 + lane) << 4)) =
        make_uint4(d[0], d[1], d[2], d[3]);
  }
  for (int task = t; task < 1024; task += nthr) {  // Wp1[0:64][0:128]
    const int n = task & 127;
    const int kb = task >> 7;
    const int k0 = kb << 3;
    unsigned int d[4];
#pragma unroll
    for (int i = 0; i < 4; ++i)
      d[i] = pack2bf(Wp1[(k0 + 2 * i) * 128 + n], Wp1[(k0 + 2 * i + 1) * 128 + n]);
    const int lane = ((kb & 3) << 4) | (n & 15);
    const int frag = ((kb >> 2) << 3) | (n >> 4);
    *(uint4*)(ws + WS_WP1 + ((size_t)(frag * 64 + lane) << 4)) =
        make_uint4(d[0], d[1], d[2], d[3]);
  }
  float* misc = (float*)(ws + WS_MISC);
  for (int i = t; i < 128; i += nthr) misc[i] = bx1[i];
  for (int i = t; i < 64; i += nthr) misc[128 + i] = bx2[i];
  for (int i = t; i < 128; i += nthr) misc[192 + i] = bp1[i];
  for (int i = t; i < 128; i += nthr) misc[320 + i] = Wp2[i];
  if (t == 0) misc[448] = bp2[0];
  for (int i = t; i < 128; i += nthr) misc[456 + i] = Wx1[128 * 128 + i];
}

// ---- counting sort by col ----
__global__ __launch_bounds__(256) void hist_kernel(const int* __restrict__ ei,
                                                   int* __restrict__ counts) {
  const int t = blockIdx.x * 256 + threadIdx.x;
  if (t < EDGES) {
    int c = __builtin_nontemporal_load(ei + EDGES + t);
    c = (c < 0) ? 0 : ((c >= NODES) ? NODES - 1 : c);
    atomicAdd(&counts[c], 1);
  }
}

#define SCB 98  // blocks of 1024: 98*1024 = 100352 >= NODES+128

__global__ __launch_bounds__(1024) void scan1_kernel(const int* __restrict__ counts,
                                                     int* __restrict__ tmp,
                                                     int* __restrict__ bsum) {
  __shared__ int part[1024];
  const int t = threadIdx.x;
  const int i = blockIdx.x * 1024 + t;
  int v = (i < NODES) ? counts[i] : 0;
  part[t] = v;
  __syncthreads();
  for (int d = 1; d < 1024; d <<= 1) {
    int u = 0;
    if (t >= d) u = part[t - d];
    __syncthreads();
    if (t >= d) part[t] += u;
    __syncthreads();
  }
  tmp[i] = part[t];  // inclusive scan within block
  if (t == 1023) bsum[blockIdx.x] = part[1023];
}

__global__ __launch_bounds__(128) void scan2_kernel(const int* __restrict__ bsum,
                                                    int* __restrict__ bsumx) {
  __shared__ int part[128];
  const int t = threadIdx.x;
  int v = (t < SCB) ? bsum[t] : 0;
  part[t] = v;
  __syncthreads();
  for (int d = 1; d < 128; d <<= 1) {
    int u = 0;
    if (t >= d) u = part[t - d];
    __syncthreads();
    if (t >= d) part[t] += u;
    __syncthreads();
  }
  bsumx[t] = part[t] - v;  // exclusive
}

__global__ __launch_bounds__(1024) void scan3_kernel(const int* __restrict__ counts,
                                                     const int* __restrict__ tmp,
                                                     const int* __restrict__ bsumx,
                                                     int* __restrict__ off,
                                                     int* __restrict__ cursor) {
  const int i = blockIdx.x * 1024 + threadIdx.x;
  if (i < NODES) {
    const int cn = counts[i];  // read before cursor write (aliased with counts)
    const int o = bsumx[blockIdx.x] + tmp[i] - cn;
    off[i] = o;
    cursor[i] = o;
  } else if (i < NODES + 128) {
    off[i] = EDGES;
  }
}

__global__ __launch_bounds__(256) void scatter_kernel(const int* __restrict__ ei,
                                                      int* __restrict__ cursor,
                                                      unsigned int* __restrict__ srec) {
  const int t = blockIdx.x * 256 + threadIdx.x;
  if (t < EDGES) {
    int r = __builtin_nontemporal_load(ei + t);
    int c = __builtin_nontemporal_load(ei + EDGES + t);
    r = (r < 0) ? 0 : ((r >= NODES) ? NODES - 1 : r);
    c = (c < 0) ? 0 : ((c >= NODES) ? NODES - 1 : c);
    const int p = atomicAdd(&cursor[c], 1);
    srec[2 * (size_t)p] = (unsigned)r;
    srec[2 * (size_t)p + 1] = (unsigned)c;
  }
}

// ---- main: node-centric, zero global atomics ----
// R6 lesson kept: kt loops stay unroll(1) so the scheduler can't hoist
// whole A-frag matrices (that was the r3-r5 scratch-spill). New in r7:
// coalesced 16-lane-per-row gather, block-resident col rows (sXcol),
// mm-paired MFMA loops (1 A-load -> 2 MFMAs).
__global__ __launch_bounds__(256, 2) void node_kernel(
    const float* __restrict__ x, const float* __restrict__ pos,
    const unsigned char* __restrict__ ws, float* __restrict__ out) {
  __shared__ uint4 sFeat[2048];                    // 32 KB B-operand frags
  __shared__ unsigned int sXcol[64 * 40];          // 10 KB: block's 64 col rows, bf16 (row stride 40 uints)
  __shared__ __align__(16) float sAccX[NB * 68];   // 17 KB
  __shared__ float sAccP[NB * 4];
  __shared__ float sRel[ET * 3];
  __shared__ float sDist[ET];
  __shared__ int sLC[ET];
  __shared__ int sRowE[ET];

  const int tid = threadIdx.x;
  const int lane = tid & 63;
  const int wave = tid >> 6;
  const int q = lane >> 4;
  const int nn = lane & 15;
  const int base = blockIdx.x * NB;

  const int* off = (const int*)(ws + WS_OFF);
  const unsigned int* srec = (const unsigned int*)(ws + WS_SREC);
  const uint4* wx1f = (const uint4*)(ws + WS_WX1);
  const uint4* wx2f = (const uint4*)(ws + WS_WX2);
  const uint4* wp1f = (const uint4*)(ws + WS_WP1);
  const float* misc = (const float*)(ws + WS_MISC);

  const int e0 = off[base];
  const int e1 = off[base + NB];

  for (int i = tid; i < NB * 68; i += 256) sAccX[i] = 0.f;
  if (tid < NB * 4) sAccP[tid] = 0.f;

  // ---- once per block: stage the 64 owned col rows as bf16 in LDS
  {
    const int n = tid & 63;
    const int part = tid >> 6;  // 16 floats each
    const int node = (base + n < NODES) ? base + n : NODES - 1;
    const float* src = x + (size_t)node * 64 + part * 16;
    unsigned int u[8];
#pragma unroll
    for (int j = 0; j < 4; ++j) {
      const float4 v = *(const float4*)(src + 4 * j);
      u[2 * j] = pack2bf(v.x, v.y);
      u[2 * j + 1] = pack2bf(v.z, v.w);
    }
    unsigned int* dst = sXcol + n * 40 + part * 8;
    *(uint4*)(dst) = make_uint4(u[0], u[1], u[2], u[3]);
    *(uint4*)(dst + 4) = make_uint4(u[4], u[5], u[6], u[7]);
  }
  __syncthreads();

  const int et0 = wave * 2;
  const floatx4 fzero = {0.f, 0.f, 0.f, 0.f};

#pragma unroll 1
  for (int t0 = e0; t0 < e1; t0 += ET) {
    // ---- phase A: edge records, rel_pos, dist
    if (tid < ET) {
      const int e = t0 + tid;
      int r = 0, lc = 0;
      float r0 = 0.f, r1 = 0.f, r2 = 0.f, dd = 0.f;
      if (e < e1) {
        const u32x2 rc = *(const u32x2*)(srec + 2 * (size_t)e);
        r = (int)rc[0];
        const int c = (int)rc[1];
        lc = c - base;
        lc = (lc < 0) ? 0 : ((lc > NB - 1) ? NB - 1 : lc);
        r0 = pos[3 * r + 0] - pos[3 * c + 0];
        r1 = pos[3 * r + 1] - pos[3 * c + 1];
        r2 = pos[3 * r + 2] - pos[3 * c + 2];
        dd = r0 * r0 + r1 * r1 + r2 * r2;
      }
      sRowE[tid] = r;
      sLC[tid] = lc;
      sRel[3 * tid + 0] = r0;
      sRel[3 * tid + 1] = r1;
      sRel[3 * tid + 2] = r2;
      sDist[tid] = dd;
    }
    __syncthreads();

    // ---- phase B1: coalesced row gather. 16 lanes per row (lane=kquad),
    // one dwordx4 instruction = 4 complete rows = full-line transactions.
    {
#pragma unroll
      for (int i = 0; i < 8; ++i) {
        const int s = wave * 32 + i * 4 + (lane >> 4);  // row slot = edge idx in tile
        const int kq = lane & 15;                       // k-quad (4 floats)
        const int node = sRowE[s];
        const float4 v = *(const float4*)(x + (size_t)node * 64 + kq * 4);
        const int et = s >> 4;
        const int kt = kq >> 3;
        const int fl = (((kq >> 1) & 3) << 4) | (s & 15);
        u32x2 d;
        d[0] = pack2bf(v.x, v.y);
        d[1] = pack2bf(v.z, v.w);
        *((u32x2*)&sFeat[(et * 4 + kt) * 64 + fl] + (kq & 1)) = d;
      }
    }
    // ---- phase B2: expand col rows from sXcol into frag slots (kt 2..3)
    {
      const int e = tid >> 1;
      const int hh = tid & 1;  // kt = 2+hh
      const int lc = sLC[e];
      const unsigned int* srcw = sXcol + lc * 40 + hh * 16;
      const int ml = e & 15;
      const int et = e >> 4;
#pragma unroll
      for (int oct = 0; oct < 4; ++oct) {
        const uint4 v = *(const uint4*)(srcw + oct * 4);
        sFeat[(et * 4 + 2 + hh) * 64 + ((oct << 4) | ml)] = v;
      }
    }
    __syncthreads();

    // ---- phi_pos (mm-paired: accp[2][8]=64 regs, kt unroll 1)
    {
      floatx4 accp[2][8];
#pragma unroll
      for (int m = 0; m < 2; ++m)
#pragma unroll
        for (int j = 0; j < 8; ++j) accp[m][j] = fzero;
#pragma unroll 1
      for (int kt = 0; kt < 2; ++kt) {  // x_row occupies k 0..63
        const short8 b0 = __builtin_bit_cast(short8, sFeat[((et0 + 0) * 4 + kt) * 64 + lane]);
        const short8 b1 = __builtin_bit_cast(short8, sFeat[((et0 + 1) * 4 + kt) * 64 + lane]);
#pragma unroll
        for (int jt = 0; jt < 8; ++jt) {
          const short8 a = __builtin_bit_cast(short8, wp1f[(kt * 8 + jt) * 64 + lane]);
          accp[0][jt] = MFMA(a, b0, accp[0][jt]);
          accp[1][jt] = MFMA(a, b1, accp[1][jt]);
        }
      }
      float wvv[2];
#pragma unroll
      for (int m = 0; m < 2; ++m) {
        float s = 0.f;
#pragma unroll
        for (int jt = 0; jt < 8; ++jt) {
          const float4 bp = *(const float4*)(misc + 192 + jt * 16 + q * 4);
          const float4 wp = *(const float4*)(misc + 320 + jt * 16 + q * 4);
          s += fast_silu(accp[m][jt][0] + bp.x) * wp.x;
          s += fast_silu(accp[m][jt][1] + bp.y) * wp.y;
          s += fast_silu(accp[m][jt][2] + bp.z) * wp.z;
          s += fast_silu(accp[m][jt][3] + bp.w) * wp.w;
        }
        s += __shfl_xor(s, 16);
        s += __shfl_xor(s, 32);
        wvv[m] = s + misc[448];
      }
      if (q == 0) {
#pragma unroll
        for (int m = 0; m < 2; ++m) {
          const int el = (et0 + m) * 16 + nn;
          if (t0 + el < e1) {
            const int lc = sLC[el];
            atomicAdd(&sAccP[lc * 4 + 0], wvv[m] * sRel[3 * el + 0]);
            atomicAdd(&sAccP[lc * 4 + 1], wvv[m] * sRel[3 * el + 1]);
            atomicAdd(&sAccP[lc * 4 + 2], wvv[m] * sRel[3 * el + 2]);
          }
        }
      }
    }

    // ---- GEMM1 (mm-paired) + epilogue 1
    {
      floatx4 acc1[2][8];
#pragma unroll
      for (int m = 0; m < 2; ++m)
#pragma unroll
        for (int j = 0; j < 8; ++j) acc1[m][j] = fzero;
#pragma unroll 1
      for (int kt = 0; kt < 4; ++kt) {
        const short8 b0 = __builtin_bit_cast(short8, sFeat[((et0 + 0) * 4 + kt) * 64 + lane]);
        const short8 b1 = __builtin_bit_cast(short8, sFeat[((et0 + 1) * 4 + kt) * 64 + lane]);
#pragma unroll
        for (int jt = 0; jt < 8; ++jt) {
          const short8 a = __builtin_bit_cast(short8, wx1f[(kt * 8 + jt) * 64 + lane]);
          acc1[0][jt] = MFMA(a, b0, acc1[0][jt]);
          acc1[1][jt] = MFMA(a, b1, acc1[1][jt]);
        }
      }
#pragma unroll
      for (int m = 0; m < 2; ++m) {
        const int etG = et0 + m;
        const float dist = sDist[etG * 16 + nn];
#pragma unroll
        for (int jt = 0; jt < 8; ++jt) {
          const float4 bx = *(const float4*)(misc + 0 + jt * 16 + q * 4);
          const float4 wd = *(const float4*)(misc + 456 + jt * 16 + q * 4);
          const unsigned int h01 = pack2bf(fast_silu(acc1[m][jt][0] + bx.x + dist * wd.x),
                                           fast_silu(acc1[m][jt][1] + bx.y + dist * wd.y));
          const unsigned int h23 = pack2bf(fast_silu(acc1[m][jt][2] + bx.z + dist * wd.z),
                                           fast_silu(acc1[m][jt][3] + bx.w + dist * wd.w));
          const int j0 = jt * 16 + q * 4;
          const int kt2 = j0 >> 5;
          const int lane2 = (((j0 & 31) >> 3) << 4) | nn;
          const int byteoff = (j0 & 7) << 1;
          uint2* dst = (uint2*)((char*)sFeat +
                                (((size_t)((etG * 4 + kt2) * 64 + lane2)) << 4) + byteoff);
          *dst = make_uint2(h01, h23);
        }
      }
    }

    // ---- GEMM2 (mm-paired) + epilogue 2
    {
      floatx4 acc2[2][4];
#pragma unroll
      for (int m = 0; m < 2; ++m)
#pragma unroll
        for (int it = 0; it < 4; ++it) acc2[m][it] = fzero;
#pragma unroll 1
      for (int kt = 0; kt < 4; ++kt) {
        const short8 b0 = __builtin_bit_cast(short8, sFeat[((et0 + 0) * 4 + kt) * 64 + lane]);
        const short8 b1 = __builtin_bit_cast(short8, sFeat[((et0 + 1) * 4 + kt) * 64 + lane]);
#pragma unroll
        for (int it = 0; it < 4; ++it) {
          const short8 a = __builtin_bit_cast(short8, wx2f[(kt * 4 + it) * 64 + lane]);
          acc2[0][it] = MFMA(a, b0, acc2[0][it]);
          acc2[1][it] = MFMA(a, b1, acc2[1][it]);
        }
      }
#pragma unroll
      for (int m = 0; m < 2; ++m) {
        const int el = (et0 + m) * 16 + nn;
        const bool v = (t0 + el) < e1;
        const int lc = sLC[el];
        float* arow = sAccX + lc * 68;
#pragma unroll
        for (int it = 0; it < 4; ++it) {
          const float4 b2 = *(const float4*)(misc + 128 + it * 16 + q * 4);
          if (v) {
            const int i0 = it * 16 + q * 4;
            atomicAdd(arow + i0 + 0, acc2[m][it][0] + b2.x);
            atomicAdd(arow + i0 + 1, acc2[m][it][1] + b2.y);
            atomicAdd(arow + i0 + 2, acc2[m][it][2] + b2.z);
            atomicAdd(arow + i0 + 3, acc2[m][it][3] + b2.w);
          }
        }
      }
    }
    __syncthreads();
  }

  // ---- final coalesced stores (no global atomics)
  {
    const int n = base + (tid >> 2);
    if (n < NODES) {
      const int c0 = (tid & 3) * 16;
      float* orow = out + (size_t)n * 64 + c0;
      const float* arow = sAccX + (tid >> 2) * 68 + c0;
#pragma unroll
      for (int j = 0; j < 16; j += 4) *(float4*)(orow + j) = *(const float4*)(arow + j);
    }
    if (tid < 192) {
      const int idx = base * 3 + tid;
      if (idx < NODES * 3)
        out[(size_t)NODES * 64 + idx] = sAccP[(tid / 3) * 4 + (tid % 3)];
    }
  }
}

extern "C" void kernel_launch(void* const* d_in, const int* in_sizes, int n_in,
                              void* d_out, int out_size, void* d_ws, size_t ws_size,
                              hipStream_t stream) {
  (void)in_sizes; (void)n_in; (void)ws_size; (void)out_size;
  const float* x = (const float*)d_in[0];
  const float* pos = (const float*)d_in[1];
  const int* ei = (const int*)d_in[2];
  const float* Wx1 = (const float*)d_in[3];
  const float* bx1 = (const float*)d_in[4];
  const float* Wx2 = (const float*)d_in[5];
  const float* bx2 = (const float*)d_in[6];
  const float* Wp1 = (const float*)d_in[7];
  const float* bp1 = (const float*)d_in[8];
  const float* Wp2 = (const float*)d_in[9];
  const float* bp2 = (const float*)d_in[10];
  float* out = (float*)d_out;
  unsigned char* ws = (unsigned char*)d_ws;

  int* counts = (int*)(ws + WS_CNT);   // aliased with cursor (scan3 rewrites)
  int* cursor = (int*)(ws + WS_CNT);
  int* off = (int*)(ws + WS_OFF);
  int* tmp = (int*)(ws + WS_TMP);      // aliased with srec (dies before scatter)
  int* bsum = (int*)(ws + WS_BSUM);
  int* bsumx = (int*)(ws + WS_BSUMX);
  unsigned int* srec = (unsigned int*)(ws + WS_SREC);

  hipMemsetAsync(counts, 0, (size_t)NODES * sizeof(int), stream);
  prep_kernel<<<16, 256, 0, stream>>>(Wx1, Wx2, Wp1, bx1, bx2, bp1, Wp2, bp2, ws);
  const int eb = (EDGES + 255) / 256;
  hist_kernel<<<eb, 256, 0, stream>>>(ei, counts);
  scan1_kernel<<<SCB, 1024, 0, stream>>>(counts, tmp, bsum);
  scan2_kernel<<<1, 128, 0, stream>>>(bsum, bsumx);
  scan3_kernel<<<SCB, 1024, 0, stream>>>(counts, tmp, bsumx, off, cursor);
  scatter_kernel<<<eb, 256, 0, stream>>>(ei, cursor, srec);
  node_kernel<<<NBLK, 256, 0, stream>>>(x, pos, ws, out);
}

// Round 9
// 852.705 us; speedup vs baseline: 1.1699x; 1.1699x over previous
//
#include <hip/hip_runtime.h>

#define EDGES 1000000
#define NODES 100000
#define ET 128   // edges per tile
#define NB 64    // nodes per block (node_kernel)
#define NBLK ((NODES + NB - 1) / NB)  // 1563

typedef short short8 __attribute__((ext_vector_type(8)));
typedef float floatx4 __attribute__((ext_vector_type(4)));
typedef unsigned int u32x2 __attribute__((ext_vector_type(2)));

#define MFMA(a, b, c) __builtin_amdgcn_mfma_f32_16x16x32_bf16(a, b, c, 0, 0, 0)

// ws layout (bytes)
#define WS_WX1 0        // 32768: Wx1 bf16 frags
#define WS_WX2 32768    // 16384: Wx2 frags
#define WS_WP1 49152    // 16384: Wp1 frags
#define WS_MISC 65536   // 2048: biases etc (floats)
#define WS_OFF 68608    // off[100128] int = 400512 B (CSR offsets, padded)
#define WS_CNT 469504   // counts/cursor[100000] int = 400000 B (aliased)
#define WS_SREC 917504  // uint2[EDGES] = 8 MB sorted (row,col) records
// scan temporaries alias the srec region (they die before scatter writes srec):
#define WS_TMP WS_SREC                 // int[100352] inclusive per-block scans
#define WS_BSUM (WS_SREC + 401408)     // int[98] block sums
#define WS_BSUMX (WS_SREC + 402432)    // int[128] exclusive-scanned block sums

__device__ __forceinline__ unsigned short f2bf(float f) {
  union { float f; unsigned int u; } c;
  c.f = f;
  unsigned int u = c.u;
  u += 0x7fffu + ((u >> 16) & 1u);
  return (unsigned short)(u >> 16);
}

__device__ __forceinline__ unsigned int pack2bf(float lo, float hi) {
  return (unsigned int)f2bf(lo) | ((unsigned int)f2bf(hi) << 16);
}

__device__ __forceinline__ float fast_silu(float v) {
#if __has_builtin(__builtin_amdgcn_exp2f) && __has_builtin(__builtin_amdgcn_rcpf)
  float e = __builtin_amdgcn_exp2f(-1.44269504088896340736f * v);
  return v * __builtin_amdgcn_rcpf(1.0f + e);
#else
  return v / (1.0f + __expf(-v));
#endif
}

// DPP cross-lane within 16-lane rows. row_shr:N = lane i reads lane i-N;
// row_shl:1 = lane i reads lane i+1. MUST be called unconditionally in
// straight-line code: these are convergent ops — R8 put them behind
// &&/|| short-circuits, which masked EXEC and corrupted boundary lanes.
template <int CTRL>
__device__ __forceinline__ int dpp_i(int v) {
  return __builtin_amdgcn_update_dpp(0, v, CTRL, 0xf, 0xf, true);
}
template <int CTRL>
__device__ __forceinline__ float dpp_f(float v) {
  return __builtin_bit_cast(float, dpp_i<CTRL>(__builtin_bit_cast(int, v)));
}

// Segmented inclusive prefix-sum across nn (16-lane row), segments = runs of
// equal sorted keys; masks m1..m8 from unconditional key equality at d=1,2,4,8.
__device__ __forceinline__ float segscan(float v, bool m1, bool m2, bool m4, bool m8) {
  float t;
  t = dpp_f<0x111>(v); v += m1 ? t : 0.f;
  t = dpp_f<0x112>(v); v += m2 ? t : 0.f;
  t = dpp_f<0x114>(v); v += m4 ? t : 0.f;
  t = dpp_f<0x118>(v); v += m8 ? t : 0.f;
  return v;
}

__device__ __forceinline__ void lds_add(float* p, float v) {
  __hip_atomic_fetch_add(p, v, __ATOMIC_RELAXED, __HIP_MEMORY_SCOPE_WORKGROUP);
}

__global__ __launch_bounds__(256) void prep_kernel(
    const float* __restrict__ Wx1, const float* __restrict__ Wx2,
    const float* __restrict__ Wp1, const float* __restrict__ bx1,
    const float* __restrict__ bx2, const float* __restrict__ bp1,
    const float* __restrict__ Wp2, const float* __restrict__ bp2,
    unsigned char* __restrict__ ws) {
  const int t = blockIdx.x * 256 + threadIdx.x;
  const int nthr = gridDim.x * 256;

  for (int task = t; task < 2048; task += nthr) {  // Wx1[0:128][0:128]
    const int n = task & 127;
    const int kb = task >> 7;
    const int k0 = kb << 3;
    unsigned int d[4];
#pragma unroll
    for (int i = 0; i < 4; ++i)
      d[i] = pack2bf(Wx1[(k0 + 2 * i) * 128 + n], Wx1[(k0 + 2 * i + 1) * 128 + n]);
    const int lane = ((kb & 3) << 4) | (n & 15);
    const int frag = ((kb >> 2) << 3) | (n >> 4);
    *(uint4*)(ws + WS_WX1 + ((size_t)(frag * 64 + lane) << 4)) =
        make_uint4(d[0], d[1], d[2], d[3]);
  }
  for (int task = t; task < 1024; task += nthr) {  // Wx2[0:128][0:64]
    const int n = task & 63;
    const int kb = task >> 6;
    const int k0 = kb << 3;
    unsigned int d[4];
#pragma unroll
    for (int i = 0; i < 4; ++i)
      d[i] = pack2bf(Wx2[(k0 + 2 * i) * 64 + n], Wx2[(k0 + 2 * i + 1) * 64 + n]);
    const int lane = ((kb & 3) << 4) | (n & 15);
    const int frag = ((kb >> 2) << 2) | (n >> 4);
    *(uint4*)(ws + WS_WX2 + ((size_t)(frag * 64 + lane) << 4)) =
        make_uint4(d[0], d[1], d[2], d[3]);
  }
  for (int task = t; task < 1024; task += nthr) {  // Wp1[0:64][0:128]
    const int n = task & 127;
    const int kb = task >> 7;
    const int k0 = kb << 3;
    unsigned int d[4];
#pragma unroll
    for (int i = 0; i < 4; ++i)
      d[i] = pack2bf(Wp1[(k0 + 2 * i) * 128 + n], Wp1[(k0 + 2 * i + 1) * 128 + n]);
    const int lane = ((kb & 3) << 4) | (n & 15);
    const int frag = ((kb >> 2) << 3) | (n >> 4);
    *(uint4*)(ws + WS_WP1 + ((size_t)(frag * 64 + lane) << 4)) =
        make_uint4(d[0], d[1], d[2], d[3]);
  }
  float* misc = (float*)(ws + WS_MISC);
  for (int i = t; i < 128; i += nthr) misc[i] = bx1[i];
  for (int i = t; i < 64; i += nthr) misc[128 + i] = bx2[i];
  for (int i = t; i < 128; i += nthr) misc[192 + i] = bp1[i];
  for (int i = t; i < 128; i += nthr) misc[320 + i] = Wp2[i];
  if (t == 0) misc[448] = bp2[0];
  for (int i = t; i < 128; i += nthr) misc[456 + i] = Wx1[128 * 128 + i];
}

// ---- counting sort by col ----
__global__ __launch_bounds__(256) void hist_kernel(const int* __restrict__ ei,
                                                   int* __restrict__ counts) {
  const int t = blockIdx.x * 256 + threadIdx.x;
  if (t < EDGES) {
    int c = __builtin_nontemporal_load(ei + EDGES + t);
    c = (c < 0) ? 0 : ((c >= NODES) ? NODES - 1 : c);
    atomicAdd(&counts[c], 1);
  }
}

#define SCB 98  // blocks of 1024: 98*1024 = 100352 >= NODES+128

__global__ __launch_bounds__(1024) void scan1_kernel(const int* __restrict__ counts,
                                                     int* __restrict__ tmp,
                                                     int* __restrict__ bsum) {
  __shared__ int part[1024];
  const int t = threadIdx.x;
  const int i = blockIdx.x * 1024 + t;
  int v = (i < NODES) ? counts[i] : 0;
  part[t] = v;
  __syncthreads();
  for (int d = 1; d < 1024; d <<= 1) {
    int u = 0;
    if (t >= d) u = part[t - d];
    __syncthreads();
    if (t >= d) part[t] += u;
    __syncthreads();
  }
  tmp[i] = part[t];  // inclusive scan within block
  if (t == 1023) bsum[blockIdx.x] = part[1023];
}

__global__ __launch_bounds__(128) void scan2_kernel(const int* __restrict__ bsum,
                                                    int* __restrict__ bsumx) {
  __shared__ int part[128];
  const int t = threadIdx.x;
  int v = (t < SCB) ? bsum[t] : 0;
  part[t] = v;
  __syncthreads();
  for (int d = 1; d < 128; d <<= 1) {
    int u = 0;
    if (t >= d) u = part[t - d];
    __syncthreads();
    if (t >= d) part[t] += u;
    __syncthreads();
  }
  bsumx[t] = part[t] - v;  // exclusive
}

__global__ __launch_bounds__(1024) void scan3_kernel(const int* __restrict__ counts,
                                                     const int* __restrict__ tmp,
                                                     const int* __restrict__ bsumx,
                                                     int* __restrict__ off,
                                                     int* __restrict__ cursor) {
  const int i = blockIdx.x * 1024 + threadIdx.x;
  if (i < NODES) {
    const int cn = counts[i];  // read before cursor write (aliased with counts)
    const int o = bsumx[blockIdx.x] + tmp[i] - cn;
    off[i] = o;
    cursor[i] = o;
  } else if (i < NODES + 128) {
    off[i] = EDGES;
  }
}

__global__ __launch_bounds__(256) void scatter_kernel(const int* __restrict__ ei,
                                                      int* __restrict__ cursor,
                                                      unsigned int* __restrict__ srec) {
  const int t = blockIdx.x * 256 + threadIdx.x;
  if (t < EDGES) {
    int r = __builtin_nontemporal_load(ei + t);
    int c = __builtin_nontemporal_load(ei + EDGES + t);
    r = (r < 0) ? 0 : ((r >= NODES) ? NODES - 1 : r);
    c = (c < 0) ? 0 : ((c >= NODES) ? NODES - 1 : c);
    const int p = atomicAdd(&cursor[c], 1);
    srec[2 * (size_t)p] = (unsigned)r;
    srec[2 * (size_t)p + 1] = (unsigned)c;
  }
}

// ---- main: node-centric, zero global atomics ----
// R9: (a) R8's DPP segscan fixed (unconditional DPP evaluation — see dpp_i
// comment); (b) sXcol dropped, cols gathered with the same coalesced
// 16-lane-per-row pattern as rows (sorted cols -> L1 hits); (c) pos
// accumulator folded into sAccX's stride-68 padding: LDS 53248 B -> 3
// blocks/CU. kt loops stay unroll(1) (anti-spill, r3-r5 lesson).
__global__ __launch_bounds__(256, 3) void node_kernel(
    const float* __restrict__ x, const float* __restrict__ pos,
    const unsigned char* __restrict__ ws, float* __restrict__ out) {
  __shared__ uint4 sFeat[2048];                    // 32 KB B-operand frags
  __shared__ __align__(16) float sAccX[NB * 68];   // 17 KB; cols 64..66 = pos acc
  __shared__ float sRel[ET * 3];
  __shared__ float sDist[ET];
  __shared__ int sLC[ET];
  __shared__ int sRowE[ET];

  const int tid = threadIdx.x;
  const int lane = tid & 63;
  const int wave = tid >> 6;
  const int q = lane >> 4;
  const int nn = lane & 15;
  const int base = blockIdx.x * NB;

  const int* off = (const int*)(ws + WS_OFF);
  const unsigned int* srec = (const unsigned int*)(ws + WS_SREC);
  const uint4* wx1f = (const uint4*)(ws + WS_WX1);
  const uint4* wx2f = (const uint4*)(ws + WS_WX2);
  const uint4* wp1f = (const uint4*)(ws + WS_WP1);
  const float* misc = (const float*)(ws + WS_MISC);

  const int e0 = off[base];
  const int e1 = off[base + NB];

  for (int i = tid; i < NB * 68; i += 256) sAccX[i] = 0.f;
  __syncthreads();

  const int et0 = wave * 2;
  const floatx4 fzero = {0.f, 0.f, 0.f, 0.f};

#pragma unroll 1
  for (int t0 = e0; t0 < e1; t0 += ET) {
    // ---- phase A: edge records, rel_pos, dist
    if (tid < ET) {
      const int e = t0 + tid;
      int r = 0, lc = 0;
      float r0 = 0.f, r1 = 0.f, r2 = 0.f, dd = 0.f;
      if (e < e1) {
        const u32x2 rc = *(const u32x2*)(srec + 2 * (size_t)e);
        r = (int)rc[0];
        const int c = (int)rc[1];
        lc = c - base;
        lc = (lc < 0) ? 0 : ((lc > NB - 1) ? NB - 1 : lc);
        r0 = pos[3 * r + 0] - pos[3 * c + 0];
        r1 = pos[3 * r + 1] - pos[3 * c + 1];
        r2 = pos[3 * r + 2] - pos[3 * c + 2];
        dd = r0 * r0 + r1 * r1 + r2 * r2;
      }
      sRowE[tid] = r;
      sLC[tid] = lc;
      sRel[3 * tid + 0] = r0;
      sRel[3 * tid + 1] = r1;
      sRel[3 * tid + 2] = r2;
      sDist[tid] = dd;
    }
    __syncthreads();

    // ---- phase B: coalesced gathers, 16 lanes per node row.
    // half 0: x[row] -> kt 0..1 ; half 1: x[col] -> kt 2..3 (sorted, L1-hot)
#pragma unroll 1
    for (int half = 0; half < 2; ++half) {
#pragma unroll 1
      for (int i = 0; i < 8; ++i) {
        const int s = wave * 32 + i * 4 + (lane >> 4);  // edge slot in tile
        const int kq = lane & 15;                       // k-quad (4 floats)
        const int node = half ? (base + sLC[s]) : sRowE[s];
        const float4 v = *(const float4*)(x + (size_t)node * 64 + kq * 4);
        const int et = s >> 4;
        const int kt = (half << 1) | (kq >> 3);
        const int fl = (((kq >> 1) & 3) << 4) | (s & 15);
        u32x2 d;
        d[0] = pack2bf(v.x, v.y);
        d[1] = pack2bf(v.z, v.w);
        *((u32x2*)&sFeat[(et * 4 + kt) * 64 + fl] + (kq & 1)) = d;
      }
    }
    __syncthreads();

    // ---- phi_pos (mm-paired, kt unroll 1) + segmented-scan scatter
    {
      floatx4 accp[2][8];
#pragma unroll
      for (int m = 0; m < 2; ++m)
#pragma unroll
        for (int j = 0; j < 8; ++j) accp[m][j] = fzero;
#pragma unroll 1
      for (int kt = 0; kt < 2; ++kt) {  // x_row occupies k 0..63
        const short8 b0 = __builtin_bit_cast(short8, sFeat[((et0 + 0) * 4 + kt) * 64 + lane]);
        const short8 b1 = __builtin_bit_cast(short8, sFeat[((et0 + 1) * 4 + kt) * 64 + lane]);
#pragma unroll
        for (int jt = 0; jt < 8; ++jt) {
          const short8 a = __builtin_bit_cast(short8, wp1f[(kt * 8 + jt) * 64 + lane]);
          accp[0][jt] = MFMA(a, b0, accp[0][jt]);
          accp[1][jt] = MFMA(a, b1, accp[1][jt]);
        }
      }
#pragma unroll
      for (int m = 0; m < 2; ++m) {
        float s = 0.f;
#pragma unroll
        for (int jt = 0; jt < 8; ++jt) {
          const float4 bp = *(const float4*)(misc + 192 + jt * 16 + q * 4);
          const float4 wp = *(const float4*)(misc + 320 + jt * 16 + q * 4);
          s += fast_silu(accp[m][jt][0] + bp.x) * wp.x;
          s += fast_silu(accp[m][jt][1] + bp.y) * wp.y;
          s += fast_silu(accp[m][jt][2] + bp.z) * wp.z;
          s += fast_silu(accp[m][jt][3] + bp.w) * wp.w;
        }
        s += __shfl_xor(s, 16);
        s += __shfl_xor(s, 32);
        const float wv = s + misc[448];  // all 64 lanes hold per-nn value

        const int el = (et0 + m) * 16 + nn;
        const bool vE = (t0 + el) < e1;
        int lcv = sLC[el];
        if (!vE) lcv = -1 - nn;  // singleton segments for invalid lanes
        // unconditional DPPs (convergent!) then bitwise combines:
        const int k1 = dpp_i<0x111>(lcv);
        const int k2 = dpp_i<0x112>(lcv);
        const int k4 = dpp_i<0x114>(lcv);
        const int k8 = dpp_i<0x118>(lcv);
        const int kn = dpp_i<0x101>(lcv);
        const bool m1 = (nn >= 1) & (k1 == lcv);
        const bool m2 = (nn >= 2) & (k2 == lcv);
        const bool m4 = (nn >= 4) & (k4 == lcv);
        const bool m8 = (nn >= 8) & (k8 == lcv);
        const bool tail = vE & ((nn == 15) | (kn != lcv));

        float p0 = segscan(wv * sRel[3 * el + 0], m1, m2, m4, m8);
        float p1 = segscan(wv * sRel[3 * el + 1], m1, m2, m4, m8);
        float p2 = segscan(wv * sRel[3 * el + 2], m1, m2, m4, m8);
        if (tail && q == 0) {
          float* ap = sAccX + lcv * 68 + 64;  // pos acc lives in the pad
          lds_add(ap + 0, p0);
          lds_add(ap + 1, p1);
          lds_add(ap + 2, p2);
        }
      }
    }

    // ---- GEMM1 (mm-paired) + epilogue 1
    {
      floatx4 acc1[2][8];
#pragma unroll
      for (int m = 0; m < 2; ++m)
#pragma unroll
        for (int j = 0; j < 8; ++j) acc1[m][j] = fzero;
#pragma unroll 1
      for (int kt = 0; kt < 4; ++kt) {
        const short8 b0 = __builtin_bit_cast(short8, sFeat[((et0 + 0) * 4 + kt) * 64 + lane]);
        const short8 b1 = __builtin_bit_cast(short8, sFeat[((et0 + 1) * 4 + kt) * 64 + lane]);
#pragma unroll
        for (int jt = 0; jt < 8; ++jt) {
          const short8 a = __builtin_bit_cast(short8, wx1f[(kt * 8 + jt) * 64 + lane]);
          acc1[0][jt] = MFMA(a, b0, acc1[0][jt]);
          acc1[1][jt] = MFMA(a, b1, acc1[1][jt]);
        }
      }
#pragma unroll
      for (int m = 0; m < 2; ++m) {
        const int etG = et0 + m;
        const float dist = sDist[etG * 16 + nn];
#pragma unroll
        for (int jt = 0; jt < 8; ++jt) {
          const float4 bx = *(const float4*)(misc + 0 + jt * 16 + q * 4);
          const float4 wd = *(const float4*)(misc + 456 + jt * 16 + q * 4);
          const unsigned int h01 = pack2bf(fast_silu(acc1[m][jt][0] + bx.x + dist * wd.x),
                                           fast_silu(acc1[m][jt][1] + bx.y + dist * wd.y));
          const unsigned int h23 = pack2bf(fast_silu(acc1[m][jt][2] + bx.z + dist * wd.z),
                                           fast_silu(acc1[m][jt][3] + bx.w + dist * wd.w));
          const int j0 = jt * 16 + q * 4;
          const int kt2 = j0 >> 5;
          const int lane2 = (((j0 & 31) >> 3) << 4) | nn;
          const int byteoff = (j0 & 7) << 1;
          uint2* dst = (uint2*)((char*)sFeat +
                                (((size_t)((etG * 4 + kt2) * 64 + lane2)) << 4) + byteoff);
          *dst = make_uint2(h01, h23);
        }
      }
    }

    // ---- GEMM2 (mm-paired) + segmented-scan scatter epilogue
    {
      floatx4 acc2[2][4];
#pragma unroll
      for (int m = 0; m < 2; ++m)
#pragma unroll
        for (int it = 0; it < 4; ++it) acc2[m][it] = fzero;
#pragma unroll 1
      for (int kt = 0; kt < 4; ++kt) {
        const short8 b0 = __builtin_bit_cast(short8, sFeat[((et0 + 0) * 4 + kt) * 64 + lane]);
        const short8 b1 = __builtin_bit_cast(short8, sFeat[((et0 + 1) * 4 + kt) * 64 + lane]);
#pragma unroll
        for (int it = 0; it < 4; ++it) {
          const short8 a = __builtin_bit_cast(short8, wx2f[(kt * 4 + it) * 64 + lane]);
          acc2[0][it] = MFMA(a, b0, acc2[0][it]);
          acc2[1][it] = MFMA(a, b1, acc2[1][it]);
        }
      }
#pragma unroll
      for (int m = 0; m < 2; ++m) {
        const int el = (et0 + m) * 16 + nn;
        const bool vE = (t0 + el) < e1;
        int lcv = sLC[el];
        if (!vE) lcv = -1 - nn;
        const int k1 = dpp_i<0x111>(lcv);
        const int k2 = dpp_i<0x112>(lcv);
        const int k4 = dpp_i<0x114>(lcv);
        const int k8 = dpp_i<0x118>(lcv);
        const int kn = dpp_i<0x101>(lcv);
        const bool m1 = (nn >= 1) & (k1 == lcv);
        const bool m2 = (nn >= 2) & (k2 == lcv);
        const bool m4 = (nn >= 4) & (k4 == lcv);
        const bool m8 = (nn >= 8) & (k8 == lcv);
        const bool tail = vE & ((nn == 15) | (kn != lcv));
#pragma unroll
        for (int it = 0; it < 4; ++it) {
          const float4 b2 = *(const float4*)(misc + 128 + it * 16 + q * 4);
          float v0 = segscan(acc2[m][it][0] + b2.x, m1, m2, m4, m8);
          float v1 = segscan(acc2[m][it][1] + b2.y, m1, m2, m4, m8);
          float v2 = segscan(acc2[m][it][2] + b2.z, m1, m2, m4, m8);
          float v3 = segscan(acc2[m][it][3] + b2.w, m1, m2, m4, m8);
          if (tail) {
            float* arow = sAccX + lcv * 68;
            const int i0 = it * 16 + q * 4;
            lds_add(arow + i0 + 0, v0);
            lds_add(arow + i0 + 1, v1);
            lds_add(arow + i0 + 2, v2);
            lds_add(arow + i0 + 3, v3);
          }
        }
      }
    }
    __syncthreads();
  }

  // ---- final coalesced stores (no global atomics)
  {
    const int n = base + (tid >> 2);
    if (n < NODES) {
      const int c0 = (tid & 3) * 16;
      float* orow = out + (size_t)n * 64 + c0;
      const float* arow = sAccX + (tid >> 2) * 68 + c0;
#pragma unroll
      for (int j = 0; j < 16; j += 4) *(float4*)(orow + j) = *(const float4*)(arow + j);
    }
    if (tid < 192) {
      const int idx = base * 3 + tid;
      if (idx < NODES * 3)
        out[(size_t)NODES * 64 + idx] = sAccX[(tid / 3) * 68 + 64 + (tid % 3)];
    }
  }
}

extern "C" void kernel_launch(void* const* d_in, const int* in_sizes, int n_in,
                              void* d_out, int out_size, void* d_ws, size_t ws_size,
                              hipStream_t stream) {
  (void)in_sizes; (void)n_in; (void)ws_size; (void)out_size;
  const float* x = (const float*)d_in[0];
  const float* pos = (const float*)d_in[1];
  const int* ei = (const int*)d_in[2];
  const float* Wx1 = (const float*)d_in[3];
  const float* bx1 = (const float*)d_in[4];
  const float* Wx2 = (const float*)d_in[5];
  const float* bx2 = (const float*)d_in[6];
  const float* Wp1 = (const float*)d_in[7];
  const float* bp1 = (const float*)d_in[8];
  const float* Wp2 = (const float*)d_in[9];
  const float* bp2 = (const float*)d_in[10];
  float* out = (float*)d_out;
  unsigned char* ws = (unsigned char*)d_ws;

  int* counts = (int*)(ws + WS_CNT);   // aliased with cursor (scan3 rewrites)
  int* cursor = (int*)(ws + WS_CNT);
  int* off = (int*)(ws + WS_OFF);
  int* tmp = (int*)(ws + WS_TMP);      // aliased with srec (dies before scatter)
  int* bsum = (int*)(ws + WS_BSUM);
  int* bsumx = (int*)(ws + WS_BSUMX);
  unsigned int* srec = (unsigned int*)(ws + WS_SREC);

  hipMemsetAsync(counts, 0, (size_t)NODES * sizeof(int), stream);
  prep_kernel<<<16, 256, 0, stream>>>(Wx1, Wx2, Wp1, bx1, bx2, bp1, Wp2, bp2, ws);
  const int eb = (EDGES + 255) / 256;
  hist_kernel<<<eb, 256, 0, stream>>>(ei, counts);
  scan1_kernel<<<SCB, 1024, 0, stream>>>(counts, tmp, bsum);
  scan2_kernel<<<1, 128, 0, stream>>>(bsum, bsumx);
  scan3_kernel<<<SCB, 1024, 0, stream>>>(counts, tmp, bsumx, off, cursor);
  scatter_kernel<<<eb, 256, 0, stream>>>(ei, cursor, srec);
  node_kernel<<<NBLK, 256, 0, stream>>>(x, pos, ws, out);
}